// Round 12
// baseline (92.273 us; speedup 1.0000x reference)
//
#include <hip/hip_runtime.h>
#include <cstddef>
#include <cstdint>

#define B_    8
#define C_    256
#define Himg  80
#define Wimg  80
#define HW_   6400
#define NH_   8
#define NP_   4
#define MPROJ 352

using bf16x8 = __attribute__((ext_vector_type(8))) short;
using f32x4  = __attribute__((ext_vector_type(4))) float;
using f16x8  = __attribute__((ext_vector_type(8))) _Float16;
using f16x4  = __attribute__((ext_vector_type(4))) _Float16;

__device__ __forceinline__ unsigned short f2bf(float f) {
    union { float f; uint32_t u; } v; v.f = f;
    uint32_t r = v.u + 0x7FFFu + ((v.u >> 16) & 1u);
    return (unsigned short)(r >> 16);
}
__device__ __forceinline__ float bf2f(unsigned short s) {
    union { uint32_t u; float f; } v; v.u = ((uint32_t)s) << 16;
    return v.f;
}

#define GLD16(gsrc, ldst) \
    __builtin_amdgcn_global_load_lds( \
        (const __attribute__((address_space(1))) unsigned int*)(gsrc), \
        (__attribute__((address_space(3))) unsigned int*)(ldst), 16, 0, 0)

// ---------------------------------------------------------------------------
// Kernel 0: fused weight-prep (blocks 0..639) + x transpose (blocks 640..3839).
// ---------------------------------------------------------------------------
__global__ __launch_bounds__(256) void prep_and_transpose(
        const float* __restrict__ Wv,  const float* __restrict__ bv,
        const float* __restrict__ Woff, const float* __restrict__ boff,
        const float* __restrict__ Wa,  const float* __restrict__ ba,
        const float* __restrict__ Wo,  const float* __restrict__ x,
        short* __restrict__ WcatBf, short* __restrict__ WoBf,
        float* __restrict__ bcat,   short* __restrict__ xT) {
    __shared__ float tile[64][68];
    const int bid = blockIdx.x;
    const int t = threadIdx.x;
    if (bid < 640) {
        int o = bid;
        if (o < 384) {
            const float* src = nullptr; float bias = 0.f;
            if (o < 256)      { src = Wv   + (size_t)o * 256;         bias = bv[o];         }
            else if (o < 320) { src = Woff + (size_t)(o - 256) * 256; bias = boff[o - 256]; }
            else if (o < 352) { src = Wa   + (size_t)(o - 320) * 256; bias = ba[o - 320];   }
            WcatBf[(size_t)o * 256 + t] = src ? (short)f2bf(src[t]) : (short)0;
            if (t == 0) bcat[o] = bias;
        } else {
            int oo = o - 384;
            WoBf[(size_t)oo * 256 + t] = (short)f2bf(Wo[(size_t)oo * 256 + t]);
        }
        return;
    }
    const int b2 = bid - 640;
    const int p0 = (b2 % 100) * 64;
    const int k0 = ((b2 / 100) & 3) * 64;
    const int b  = b2 / 400;
    const float* xb = x + ((size_t)b * C_ + k0) * HW_ + p0;
    #pragma unroll
    for (int r = 0; r < 4; ++r) {
        int kk = r * 16 + (t >> 4);
        int pp = (t & 15) * 4;
        float4 v = *(const float4*)(xb + (size_t)kk * HW_ + pp);
        *(float4*)&tile[kk][pp] = v;
    }
    __syncthreads();
    const int pp = t >> 2, kc = (t & 3) * 16;
    short tmp[16];
    #pragma unroll
    for (int i = 0; i < 16; ++i) tmp[i] = (short)f2bf(tile[kc + i][pp]);
    short* dst = xT + ((size_t)b * HW_ + p0 + pp) * 256 + k0 + kc;
    *(bf16x8*)dst       = *(bf16x8*)tmp;
    *(bf16x8*)(dst + 8) = *(bf16x8*)(tmp + 8);
}

// ---------------------------------------------------------------------------
// Kernel 1: projection GEMM, 128(o) x 128(p), BK=64, counted-vmcnt pipeline.
// pt-major tile order within XCD. Epilogue: value -> head-major bf16
// val[b][h][p][32]; offsets *39.5 -> f16 meta[0..63]; attn softmax -> f16
// meta[64..95].
// ---------------------------------------------------------------------------
#define PSTAGE(buf, k0)                                                         \
    _Pragma("unroll")                                                           \
    for (int q = 0; q < 4; ++q) {                                               \
        int i = wid * 4 + q;                                                    \
        int row = i * 8 + (lane >> 3);                                          \
        int sc  = (lane & 7) ^ (row & 7);                                       \
        GLD16(Wb  + (size_t)(o0 + row) * 256 + (k0) + sc * 8,                   \
              &lA[(buf)][i * 512]);                                             \
        GLD16(xTb + (size_t)(p0 + row) * 256 + (k0) + sc * 8,                   \
              &lB[(buf)][i * 512]);                                             \
    }

#define PCOMPUTE(buf)                                                           \
    _Pragma("unroll")                                                           \
    for (int kk = 0; kk < 2; ++kk) {                                            \
        bf16x8 af[4], bfr[4];                                                   \
        _Pragma("unroll")                                                       \
        for (int m = 0; m < 4; ++m) {                                           \
            int row = wo0 + m * 16 + (lane & 15);                               \
            int cph = (kk * 4 + (lane >> 4)) ^ (row & 7);                       \
            af[m] = *(const bf16x8*)&lA[(buf)][row * 64 + cph * 8];             \
        }                                                                       \
        _Pragma("unroll")                                                       \
        for (int nn = 0; nn < 4; ++nn) {                                        \
            int row = wp0 + nn * 16 + (lane & 15);                              \
            int cph = (kk * 4 + (lane >> 4)) ^ (row & 7);                       \
            bfr[nn] = *(const bf16x8*)&lB[(buf)][row * 64 + cph * 8];           \
        }                                                                       \
        __builtin_amdgcn_s_setprio(1);                                          \
        _Pragma("unroll")                                                       \
        for (int m = 0; m < 4; ++m)                                             \
            _Pragma("unroll")                                                   \
            for (int nn = 0; nn < 4; ++nn)                                      \
                acc[m][nn] = __builtin_amdgcn_mfma_f32_16x16x32_bf16(           \
                    af[m], bfr[nn], acc[m][nn], 0, 0, 0);                       \
        __builtin_amdgcn_s_setprio(0);                                          \
    }

__global__ __launch_bounds__(256) void gemm_proj_mfma(
        const short* __restrict__ Wb, const float* __restrict__ bcat,
        const short* __restrict__ xT,
        short* __restrict__ val, _Float16* __restrict__ meta) {
    __shared__ short lA[2][8192];
    __shared__ short lB[2][8192];
    const int n = blockIdx.x;
    const int w = (n & 7) * 150 + (n >> 3);
    const int b = w / 150;
    const int r150 = w % 150;
    const int o0 = (r150 % 3) * 128;      // pt-major: o-tile fastest
    const int p0 = (r150 / 3) * 128;
    const int t = threadIdx.x;
    const int wid = t >> 6, lane = t & 63;
    const int wo0 = (wid & 1) * 64, wp0 = (wid >> 1) * 64;
    const short* xTb = xT + (size_t)b * HW_ * 256;
    f32x4 acc[4][4] = {};

    PSTAGE(0, 0)
    #pragma unroll
    for (int kt = 0; kt < 4; ++kt) {
        const int cur = kt & 1;
        if (kt > 0) __builtin_amdgcn_s_barrier();         // retire T(kt-1) readers
        if (kt < 3) { PSTAGE(cur ^ 1, (kt + 1) * 64) }    // prefetch stays in flight
        if (kt < 3) { asm volatile("s_waitcnt vmcnt(8)" ::: "memory"); }
        else        { asm volatile("s_waitcnt vmcnt(0)" ::: "memory"); }
        __builtin_amdgcn_sched_barrier(0);
        __builtin_amdgcn_s_barrier();                     // all waves' S(kt) landed
        PCOMPUTE(cur)
    }

    #pragma unroll
    for (int m = 0; m < 4; ++m) {
        int oc = o0 + wo0 + m * 16 + (lane >> 4) * 4;
        if (oc >= MPROJ) continue;
        float4 bias = *(const float4*)(bcat + oc);
        #pragma unroll
        for (int nn = 0; nn < 4; ++nn) {
            int p = p0 + wp0 + nn * 16 + (lane & 15);
            f32x4 a = acc[m][nn];
            float v0 = a[0] + bias.x, v1 = a[1] + bias.y;
            float v2 = a[2] + bias.z, v3 = a[3] + bias.w;
            if (oc < 256) {
                int h = oc >> 5, c0 = oc & 31;
                ushort4 u;
                u.x = f2bf(v0); u.y = f2bf(v1); u.z = f2bf(v2); u.w = f2bf(v3);
                *(ushort4*)(val + (((size_t)(b * NH_ + h) * HW_) + p) * 32 + c0) = u;
            } else if (oc < 320) {
                f16x4 f;
                f[0] = (_Float16)(v0 * 39.5f); f[1] = (_Float16)(v1 * 39.5f);
                f[2] = (_Float16)(v2 * 39.5f); f[3] = (_Float16)(v3 * 39.5f);
                *(f16x4*)(meta + ((size_t)b * HW_ + p) * 96 + (oc - 256)) = f;
            } else {
                float mx = fmaxf(fmaxf(v0, v1), fmaxf(v2, v3));
                float e0 = __expf(v0 - mx), e1 = __expf(v1 - mx);
                float e2 = __expf(v2 - mx), e3 = __expf(v3 - mx);
                float inv = 1.f / (e0 + e1 + e2 + e3);
                f16x4 f;
                f[0] = (_Float16)(e0 * inv); f[1] = (_Float16)(e1 * inv);
                f[2] = (_Float16)(e2 * inv); f[3] = (_Float16)(e3 * inv);
                *(f16x4*)(meta + ((size_t)b * HW_ + p) * 96 + (oc - 256)) = f;
            }
        }
    }
}

// ---------------------------------------------------------------------------
// Kernel 2: bilinear sampling + point-weighted sum (softmax precomputed, f16).
// One wave per pixel: lane = h*8 + cg*2 + s; s selects the x0/x1 corner
// column so corner pairs merge into 128B segments in one instruction.
// Pair-merge via __shfl_xor(.,1); s==0 lane stores. Grid 12800, b=orig&7.
// ---------------------------------------------------------------------------
__global__ __launch_bounds__(256) void sample_kern(
        const short* __restrict__ val, const _Float16* __restrict__ meta,
        short* __restrict__ wout) {
    const int t = threadIdx.x;
    const int wid = t >> 6, lane = t & 63;
    const int h  = lane >> 3;
    const int r  = lane & 7;
    const int cg = r >> 1;          // channel group of 8
    const int s  = r & 1;           // corner half: 0 -> x0, 1 -> x1
    const int orig = blockIdx.x;    // 0..12799
    const int b = orig & 7;
    const int p = (orig >> 3) * 4 + wid;
    const int yy = p / Wimg;
    const int xx = p - yy * Wimg;

    const _Float16* mrow = meta + ((size_t)b * HW_ + p) * 96;
    f16x4 w4 = *(const f16x4*)(mrow + 64 + h * 4);
    float wgt[4] = {(float)w4[0], (float)w4[1], (float)w4[2], (float)w4[3]};
    f16x8 off8 = *(const f16x8*)(mrow + h * 8);
    float ox[4] = {(float)off8[0], (float)off8[2], (float)off8[4], (float)off8[6]};
    float oy[4] = {(float)off8[1], (float)off8[3], (float)off8[5], (float)off8[7]};

    const short* vb = val + ((size_t)(b * NH_ + h) * HW_) * 32 + cg * 8;

    float acc[8] = {};
    #pragma unroll
    for (int pt = 0; pt < NP_; ++pt) {
        float ix = (float)xx + ox[pt];
        float iy = (float)yy + oy[pt];
        float x0f = floorf(ix), y0f = floorf(iy);
        int   x0  = (int)x0f,   y0  = (int)y0f;
        float wx1 = ix - x0f, wx0 = 1.f - wx1;
        float wy1 = iy - y0f, wy0 = 1.f - wy1;
        int xs = x0 + s;
        int xc = min(max(xs, 0), Wimg - 1);
        int y0c = min(max(y0, 0), Himg - 1), y1c = min(max(y0 + 1, 0), Himg - 1);
        float vxs = s ? wx1 : wx0;
        vxs = (xs >= 0 && xs <= Wimg - 1) ? vxs : 0.f;
        float vy0 = (y0 >= 0 && y0 <= Himg - 1)         ? wy0 : 0.f;
        float vy1 = (y0 + 1 >= 0 && y0 + 1 <= Himg - 1) ? wy1 : 0.f;
        bf16x8 u0 = *(const bf16x8*)(vb + (size_t)(y0c * Wimg + xc) * 32);
        bf16x8 u1 = *(const bf16x8*)(vb + (size_t)(y1c * Wimg + xc) * 32);
        float wA = vy0 * vxs * wgt[pt], wB = vy1 * vxs * wgt[pt];
        #pragma unroll
        for (int c = 0; c < 8; ++c)
            acc[c] += wA * bf2f((unsigned short)u0[c])
                    + wB * bf2f((unsigned short)u1[c]);
    }
    #pragma unroll
    for (int c = 0; c < 8; ++c)
        acc[c] += __shfl_xor(acc[c], 1);
    if (s == 0) {
        short tmp[8];
        #pragma unroll
        for (int c = 0; c < 8; ++c) tmp[c] = (short)f2bf(acc[c]);
        *(bf16x8*)(wout + ((size_t)b * HW_ + p) * 256 + h * 32 + cg * 8) = *(bf16x8*)tmp;
    }
}

// ---------------------------------------------------------------------------
// Kernel 3: output GEMM + bias + residual, 64(o) x 128(p), BK=64,
// counted-vmcnt pipeline. pt-major tile order within XCD.
// ---------------------------------------------------------------------------
#define OSTAGE(buf, k0)                                                         \
    _Pragma("unroll")                                                           \
    for (int q = 0; q < 2; ++q) {                                               \
        int i = wid * 2 + q;                                                    \
        int row = i * 8 + (lane >> 3);                                          \
        int sc  = (lane & 7) ^ (row & 7);                                       \
        GLD16(Wb + (size_t)(o0 + row) * 256 + (k0) + sc * 8,                    \
              &lA[(buf)][i * 512]);                                             \
    }                                                                           \
    _Pragma("unroll")                                                           \
    for (int q = 0; q < 4; ++q) {                                               \
        int i = wid * 4 + q;                                                    \
        int row = i * 8 + (lane >> 3);                                          \
        int sc  = (lane & 7) ^ (row & 7);                                       \
        GLD16(wgtb + (size_t)(p0 + row) * 256 + (k0) + sc * 8,                  \
              &lB[(buf)][i * 512]);                                             \
    }

#define OCOMPUTE(buf)                                                           \
    _Pragma("unroll")                                                           \
    for (int kk = 0; kk < 2; ++kk) {                                            \
        bf16x8 af[4], bfr[2];                                                   \
        _Pragma("unroll")                                                       \
        for (int m = 0; m < 4; ++m) {                                           \
            int row = m * 16 + (lane & 15);                                     \
            int cph = (kk * 4 + (lane >> 4)) ^ (row & 7);                       \
            af[m] = *(const bf16x8*)&lA[(buf)][row * 64 + cph * 8];             \
        }                                                                       \
        _Pragma("unroll")                                                       \
        for (int nn = 0; nn < 2; ++nn) {                                        \
            int row = wid * 32 + nn * 16 + (lane & 15);                         \
            int cph = (kk * 4 + (lane >> 4)) ^ (row & 7);                       \
            bfr[nn] = *(const bf16x8*)&lB[(buf)][row * 64 + cph * 8];           \
        }                                                                       \
        __builtin_amdgcn_s_setprio(1);                                          \
        _Pragma("unroll")                                                       \
        for (int m = 0; m < 4; ++m)                                             \
            _Pragma("unroll")                                                   \
            for (int nn = 0; nn < 2; ++nn)                                      \
                acc[m][nn] = __builtin_amdgcn_mfma_f32_16x16x32_bf16(           \
                    af[m], bfr[nn], acc[m][nn], 0, 0, 0);                       \
        __builtin_amdgcn_s_setprio(0);                                          \
    }

__global__ __launch_bounds__(256) void gemm_out_mfma(
        const short* __restrict__ Wb, const float* __restrict__ bo,
        const short* __restrict__ wgt, const float* __restrict__ x,
        float* __restrict__ out) {
    __shared__ short lA[2][4096];
    __shared__ short lB[2][8192];
    const int n = blockIdx.x;               // 0..1599
    const int w = (n & 7) * 200 + (n >> 3);
    const int b = w / 200;
    const int r200 = w % 200;
    const int o0 = (r200 % 4) * 64;       // pt-major: o-tile fastest
    const int p0 = (r200 / 4) * 128;
    const int t = threadIdx.x;
    const int wid = t >> 6, lane = t & 63;
    const short* wgtb = wgt + (size_t)b * HW_ * 256;
    f32x4 acc[4][2] = {};

    OSTAGE(0, 0)
    #pragma unroll
    for (int kt = 0; kt < 4; ++kt) {
        const int cur = kt & 1;
        if (kt > 0) __builtin_amdgcn_s_barrier();
        if (kt < 3) { OSTAGE(cur ^ 1, (kt + 1) * 64) }
        if (kt < 3) { asm volatile("s_waitcnt vmcnt(6)" ::: "memory"); }
        else        { asm volatile("s_waitcnt vmcnt(0)" ::: "memory"); }
        __builtin_amdgcn_sched_barrier(0);
        __builtin_amdgcn_s_barrier();
        OCOMPUTE(cur)
    }

    #pragma unroll
    for (int m = 0; m < 4; ++m) {
        int oc = o0 + m * 16 + (lane >> 4) * 4;
        float4 bias = *(const float4*)(bo + oc);
        float br[4] = {bias.x, bias.y, bias.z, bias.w};
        #pragma unroll
        for (int nn = 0; nn < 2; ++nn) {
            int p = p0 + wid * 32 + nn * 16 + (lane & 15);
            f32x4 a = acc[m][nn];
            #pragma unroll
            for (int reg = 0; reg < 4; ++reg) {
                size_t ad = ((size_t)b * C_ + oc + reg) * HW_ + p;
                out[ad] = a[reg] + br[reg] + x[ad];
            }
        }
    }
}

// ---------------------------------------------------------------------------
// Launch
// ---------------------------------------------------------------------------
extern "C" void kernel_launch(void* const* d_in, const int* in_sizes, int n_in,
                              void* d_out, int out_size, void* d_ws, size_t ws_size,
                              hipStream_t stream) {
    const float* x    = (const float*)d_in[0];
    const float* Wv   = (const float*)d_in[1];
    const float* bv   = (const float*)d_in[2];
    const float* Woff = (const float*)d_in[3];
    const float* boff = (const float*)d_in[4];
    const float* Wa   = (const float*)d_in[5];
    const float* ba   = (const float*)d_in[6];
    const float* Wo   = (const float*)d_in[7];
    const float* bo   = (const float*)d_in[8];
    float* out = (float*)d_out;
    char* base = (char*)d_ws;

    short*    WcatBf = (short*)(base);               //   196608
    short*    WoBf   = (short*)(base + 196608);      //   131072
    float*    bcat   = (float*)(base + 327680);      //     1536 (+pad)
    short*    xT     = (short*)(base + 329728);      // 26214400
    short*    val    = (short*)(base + 26544128);    // 26214400
    _Float16* meta   = (_Float16*)(base + 52758528); //  9830400 (f16)
    short*    wbuf   = (short*)(base + 72419328);    // 26214400

    prep_and_transpose<<<dim3(3840), dim3(256), 0, stream>>>(
        Wv, bv, Woff, boff, Wa, ba, Wo, x, WcatBf, WoBf, bcat, xT);
    gemm_proj_mfma<<<dim3(1200), dim3(256), 0, stream>>>(WcatBf, bcat, xT, val, meta);
    sample_kern<<<dim3(12800), dim3(256), 0, stream>>>(val, meta, wbuf);
    gemm_out_mfma<<<dim3(1600), dim3(256), 0, stream>>>(WoBf, bo, wbuf, x, out);
}

// Round 13
// 90.791 us; speedup vs baseline: 1.0163x; 1.0163x over previous
//
#include <hip/hip_runtime.h>
#include <cstddef>
#include <cstdint>

#define B_    8
#define C_    256
#define Himg  80
#define Wimg  80
#define HW_   6400
#define NH_   8
#define NP_   4
#define MPROJ 352

using bf16x8 = __attribute__((ext_vector_type(8))) short;
using f32x4  = __attribute__((ext_vector_type(4))) float;
using f16x8  = __attribute__((ext_vector_type(8))) _Float16;
using f16x4  = __attribute__((ext_vector_type(4))) _Float16;

__device__ __forceinline__ unsigned short f2bf(float f) {
    union { float f; uint32_t u; } v; v.f = f;
    uint32_t r = v.u + 0x7FFFu + ((v.u >> 16) & 1u);
    return (unsigned short)(r >> 16);
}
__device__ __forceinline__ float bf2f(unsigned short s) {
    union { uint32_t u; float f; } v; v.u = ((uint32_t)s) << 16;
    return v.f;
}

#define GLD16(gsrc, ldst) \
    __builtin_amdgcn_global_load_lds( \
        (const __attribute__((address_space(1))) unsigned int*)(gsrc), \
        (__attribute__((address_space(3))) unsigned int*)(ldst), 16, 0, 0)

// ---------------------------------------------------------------------------
// Kernel 0: fused weight-prep (blocks 0..639) + x transpose (blocks 640..3839).
// ---------------------------------------------------------------------------
__global__ __launch_bounds__(256) void prep_and_transpose(
        const float* __restrict__ Wv,  const float* __restrict__ bv,
        const float* __restrict__ Woff, const float* __restrict__ boff,
        const float* __restrict__ Wa,  const float* __restrict__ ba,
        const float* __restrict__ Wo,  const float* __restrict__ x,
        short* __restrict__ WcatBf, short* __restrict__ WoBf,
        float* __restrict__ bcat,   short* __restrict__ xT) {
    __shared__ float tile[64][68];
    const int bid = blockIdx.x;
    const int t = threadIdx.x;
    if (bid < 640) {
        int o = bid;
        if (o < 384) {
            const float* src = nullptr; float bias = 0.f;
            if (o < 256)      { src = Wv   + (size_t)o * 256;         bias = bv[o];         }
            else if (o < 320) { src = Woff + (size_t)(o - 256) * 256; bias = boff[o - 256]; }
            else if (o < 352) { src = Wa   + (size_t)(o - 320) * 256; bias = ba[o - 320];   }
            WcatBf[(size_t)o * 256 + t] = src ? (short)f2bf(src[t]) : (short)0;
            if (t == 0) bcat[o] = bias;
        } else {
            int oo = o - 384;
            WoBf[(size_t)oo * 256 + t] = (short)f2bf(Wo[(size_t)oo * 256 + t]);
        }
        return;
    }
    const int b2 = bid - 640;
    const int p0 = (b2 % 100) * 64;
    const int k0 = ((b2 / 100) & 3) * 64;
    const int b  = b2 / 400;
    const float* xb = x + ((size_t)b * C_ + k0) * HW_ + p0;
    #pragma unroll
    for (int r = 0; r < 4; ++r) {
        int kk = r * 16 + (t >> 4);
        int pp = (t & 15) * 4;
        float4 v = *(const float4*)(xb + (size_t)kk * HW_ + pp);
        *(float4*)&tile[kk][pp] = v;
    }
    __syncthreads();
    const int pp = t >> 2, kc = (t & 3) * 16;
    short tmp[16];
    #pragma unroll
    for (int i = 0; i < 16; ++i) tmp[i] = (short)f2bf(tile[kc + i][pp]);
    short* dst = xT + ((size_t)b * HW_ + p0 + pp) * 256 + k0 + kc;
    *(bf16x8*)dst       = *(bf16x8*)tmp;
    *(bf16x8*)(dst + 8) = *(bf16x8*)(tmp + 8);
}

// ---------------------------------------------------------------------------
// Kernel 1: projection GEMM, 128(o) x 128(p), BK=64, counted-vmcnt pipeline.
// pt-major tile order within XCD. Epilogue: value -> head-major bf16
// val[b][h][p][32]; offsets *39.5 -> f16 meta[0..63]; attn softmax -> f16
// meta[64..95].
// ---------------------------------------------------------------------------
#define PSTAGE(buf, k0)                                                         \
    _Pragma("unroll")                                                           \
    for (int q = 0; q < 4; ++q) {                                               \
        int i = wid * 4 + q;                                                    \
        int row = i * 8 + (lane >> 3);                                          \
        int sc  = (lane & 7) ^ (row & 7);                                       \
        GLD16(Wb  + (size_t)(o0 + row) * 256 + (k0) + sc * 8,                   \
              &lA[(buf)][i * 512]);                                             \
        GLD16(xTb + (size_t)(p0 + row) * 256 + (k0) + sc * 8,                   \
              &lB[(buf)][i * 512]);                                             \
    }

#define PCOMPUTE(buf)                                                           \
    _Pragma("unroll")                                                           \
    for (int kk = 0; kk < 2; ++kk) {                                            \
        bf16x8 af[4], bfr[4];                                                   \
        _Pragma("unroll")                                                       \
        for (int m = 0; m < 4; ++m) {                                           \
            int row = wo0 + m * 16 + (lane & 15);                               \
            int cph = (kk * 4 + (lane >> 4)) ^ (row & 7);                       \
            af[m] = *(const bf16x8*)&lA[(buf)][row * 64 + cph * 8];             \
        }                                                                       \
        _Pragma("unroll")                                                       \
        for (int nn = 0; nn < 4; ++nn) {                                        \
            int row = wp0 + nn * 16 + (lane & 15);                              \
            int cph = (kk * 4 + (lane >> 4)) ^ (row & 7);                       \
            bfr[nn] = *(const bf16x8*)&lB[(buf)][row * 64 + cph * 8];           \
        }                                                                       \
        _Pragma("unroll")                                                       \
        for (int m = 0; m < 4; ++m)                                             \
            _Pragma("unroll")                                                   \
            for (int nn = 0; nn < 4; ++nn)                                      \
                acc[m][nn] = __builtin_amdgcn_mfma_f32_16x16x32_bf16(           \
                    af[m], bfr[nn], acc[m][nn], 0, 0, 0);                       \
    }

__global__ __launch_bounds__(256) void gemm_proj_mfma(
        const short* __restrict__ Wb, const float* __restrict__ bcat,
        const short* __restrict__ xT,
        short* __restrict__ val, _Float16* __restrict__ meta) {
    __shared__ short lA[2][8192];
    __shared__ short lB[2][8192];
    const int n = blockIdx.x;
    const int w = (n & 7) * 150 + (n >> 3);
    const int b = w / 150;
    const int r150 = w % 150;
    const int o0 = (r150 % 3) * 128;      // pt-major: o-tile fastest
    const int p0 = (r150 / 3) * 128;
    const int t = threadIdx.x;
    const int wid = t >> 6, lane = t & 63;
    const int wo0 = (wid & 1) * 64, wp0 = (wid >> 1) * 64;
    const short* xTb = xT + (size_t)b * HW_ * 256;
    f32x4 acc[4][4] = {};

    PSTAGE(0, 0)
    #pragma unroll
    for (int kt = 0; kt < 4; ++kt) {
        const int cur = kt & 1;
        if (kt > 0) __builtin_amdgcn_s_barrier();         // retire T(kt-1) readers
        if (kt < 3) { PSTAGE(cur ^ 1, (kt + 1) * 64) }    // prefetch stays in flight
        if (kt < 3) { asm volatile("s_waitcnt vmcnt(8)" ::: "memory"); }
        else        { asm volatile("s_waitcnt vmcnt(0)" ::: "memory"); }
        __builtin_amdgcn_sched_barrier(0);
        __builtin_amdgcn_s_barrier();                     // all waves' S(kt) landed
        PCOMPUTE(cur)
    }

    #pragma unroll
    for (int m = 0; m < 4; ++m) {
        int oc = o0 + wo0 + m * 16 + (lane >> 4) * 4;
        if (oc >= MPROJ) continue;
        float4 bias = *(const float4*)(bcat + oc);
        #pragma unroll
        for (int nn = 0; nn < 4; ++nn) {
            int p = p0 + wp0 + nn * 16 + (lane & 15);
            f32x4 a = acc[m][nn];
            float v0 = a[0] + bias.x, v1 = a[1] + bias.y;
            float v2 = a[2] + bias.z, v3 = a[3] + bias.w;
            if (oc < 256) {
                int h = oc >> 5, c0 = oc & 31;
                ushort4 u;
                u.x = f2bf(v0); u.y = f2bf(v1); u.z = f2bf(v2); u.w = f2bf(v3);
                *(ushort4*)(val + (((size_t)(b * NH_ + h) * HW_) + p) * 32 + c0) = u;
            } else if (oc < 320) {
                f16x4 f;
                f[0] = (_Float16)(v0 * 39.5f); f[1] = (_Float16)(v1 * 39.5f);
                f[2] = (_Float16)(v2 * 39.5f); f[3] = (_Float16)(v3 * 39.5f);
                *(f16x4*)(meta + ((size_t)b * HW_ + p) * 96 + (oc - 256)) = f;
            } else {
                float mx = fmaxf(fmaxf(v0, v1), fmaxf(v2, v3));
                float e0 = __expf(v0 - mx), e1 = __expf(v1 - mx);
                float e2 = __expf(v2 - mx), e3 = __expf(v3 - mx);
                float inv = 1.f / (e0 + e1 + e2 + e3);
                f16x4 f;
                f[0] = (_Float16)(e0 * inv); f[1] = (_Float16)(e1 * inv);
                f[2] = (_Float16)(e2 * inv); f[3] = (_Float16)(e3 * inv);
                *(f16x4*)(meta + ((size_t)b * HW_ + p) * 96 + (oc - 256)) = f;
            }
        }
    }
}

// ---------------------------------------------------------------------------
// Kernel 2: bilinear sampling + point-weighted sum (softmax precomputed, f16).
// Wave = 2 pixels; lane&31: h=(li>>2), j=li&3 -> channels j*8..j*8+7 (16B).
// val is head-major: corner chunk = 64B. Grid 6400, b = blockIdx&7 (XCD).
// ---------------------------------------------------------------------------
__global__ __launch_bounds__(256) void sample_kern(
        const short* __restrict__ val, const _Float16* __restrict__ meta,
        short* __restrict__ wout) {
    const int t = threadIdx.x;
    const int wid = t >> 6, lane = t & 63;
    const int sub = lane >> 5, li = lane & 31;
    const int h = li >> 2, j = li & 3;
    const int orig = blockIdx.x;
    const int b = orig & 7;
    const int p = (orig >> 3) * 8 + wid * 2 + sub;
    const int yy = p / Wimg;
    const int xx = p - yy * Wimg;

    const _Float16* mrow = meta + ((size_t)b * HW_ + p) * 96;
    f16x4 w4 = *(const f16x4*)(mrow + 64 + h * 4);
    float wgt[4] = {(float)w4[0], (float)w4[1], (float)w4[2], (float)w4[3]};

    f16x8 off8 = *(const f16x8*)(mrow + h * 8);
    float ox[4] = {(float)off8[0], (float)off8[2], (float)off8[4], (float)off8[6]};
    float oy[4] = {(float)off8[1], (float)off8[3], (float)off8[5], (float)off8[7]};

    const short* vb = val + ((size_t)(b * NH_ + h) * HW_) * 32 + j * 8;

    float acc[8] = {};
    #pragma unroll
    for (int pt = 0; pt < NP_; ++pt) {
        float ix = (float)xx + ox[pt];
        float iy = (float)yy + oy[pt];
        float x0f = floorf(ix), y0f = floorf(iy);
        int   x0  = (int)x0f,   y0  = (int)y0f;
        float wx1 = ix - x0f, wx0 = 1.f - wx1;
        float wy1 = iy - y0f, wy0 = 1.f - wy1;
        int x0c = min(max(x0, 0), Wimg - 1), x1c = min(max(x0 + 1, 0), Wimg - 1);
        int y0c = min(max(y0, 0), Himg - 1), y1c = min(max(y0 + 1, 0), Himg - 1);
        float vx0 = (x0 >= 0 && x0 <= Wimg - 1)         ? wx0 : 0.f;
        float vx1 = (x0 + 1 >= 0 && x0 + 1 <= Wimg - 1) ? wx1 : 0.f;
        float vy0 = (y0 >= 0 && y0 <= Himg - 1)         ? wy0 : 0.f;
        float vy1 = (y0 + 1 >= 0 && y0 + 1 <= Himg - 1) ? wy1 : 0.f;
        bf16x8 u00 = *(const bf16x8*)(vb + (size_t)(y0c * Wimg + x0c) * 32);
        bf16x8 u01 = *(const bf16x8*)(vb + (size_t)(y0c * Wimg + x1c) * 32);
        bf16x8 u10 = *(const bf16x8*)(vb + (size_t)(y1c * Wimg + x0c) * 32);
        bf16x8 u11 = *(const bf16x8*)(vb + (size_t)(y1c * Wimg + x1c) * 32);
        float w00 = vy0 * vx0 * wgt[pt], w01 = vy0 * vx1 * wgt[pt];
        float w10 = vy1 * vx0 * wgt[pt], w11 = vy1 * vx1 * wgt[pt];
        #pragma unroll
        for (int c = 0; c < 8; ++c) {
            acc[c] += w00 * bf2f((unsigned short)u00[c])
                    + w01 * bf2f((unsigned short)u01[c])
                    + w10 * bf2f((unsigned short)u10[c])
                    + w11 * bf2f((unsigned short)u11[c]);
        }
    }
    short tmp[8];
    #pragma unroll
    for (int c = 0; c < 8; ++c) tmp[c] = (short)f2bf(acc[c]);
    *(bf16x8*)(wout + ((size_t)b * HW_ + p) * 256 + h * 32 + j * 8) = *(bf16x8*)tmp;
}

// ---------------------------------------------------------------------------
// Kernel 3: output GEMM + bias + residual, 64(o) x 128(p), BK=64,
// counted-vmcnt pipeline. pt-major tile order within XCD.
// ---------------------------------------------------------------------------
#define OSTAGE(buf, k0)                                                         \
    _Pragma("unroll")                                                           \
    for (int q = 0; q < 2; ++q) {                                               \
        int i = wid * 2 + q;                                                    \
        int row = i * 8 + (lane >> 3);                                          \
        int sc  = (lane & 7) ^ (row & 7);                                       \
        GLD16(Wb + (size_t)(o0 + row) * 256 + (k0) + sc * 8,                    \
              &lA[(buf)][i * 512]);                                             \
    }                                                                           \
    _Pragma("unroll")                                                           \
    for (int q = 0; q < 4; ++q) {                                               \
        int i = wid * 4 + q;                                                    \
        int row = i * 8 + (lane >> 3);                                          \
        int sc  = (lane & 7) ^ (row & 7);                                       \
        GLD16(wgtb + (size_t)(p0 + row) * 256 + (k0) + sc * 8,                  \
              &lB[(buf)][i * 512]);                                             \
    }

#define OCOMPUTE(buf)                                                           \
    _Pragma("unroll")                                                           \
    for (int kk = 0; kk < 2; ++kk) {                                            \
        bf16x8 af[4], bfr[2];                                                   \
        _Pragma("unroll")                                                       \
        for (int m = 0; m < 4; ++m) {                                           \
            int row = m * 16 + (lane & 15);                                     \
            int cph = (kk * 4 + (lane >> 4)) ^ (row & 7);                       \
            af[m] = *(const bf16x8*)&lA[(buf)][row * 64 + cph * 8];             \
        }                                                                       \
        _Pragma("unroll")                                                       \
        for (int nn = 0; nn < 2; ++nn) {                                        \
            int row = wid * 32 + nn * 16 + (lane & 15);                         \
            int cph = (kk * 4 + (lane >> 4)) ^ (row & 7);                       \
            bfr[nn] = *(const bf16x8*)&lB[(buf)][row * 64 + cph * 8];           \
        }                                                                       \
        _Pragma("unroll")                                                       \
        for (int m = 0; m < 4; ++m)                                             \
            _Pragma("unroll")                                                   \
            for (int nn = 0; nn < 2; ++nn)                                      \
                acc[m][nn] = __builtin_amdgcn_mfma_f32_16x16x32_bf16(           \
                    af[m], bfr[nn], acc[m][nn], 0, 0, 0);                       \
    }

__global__ __launch_bounds__(256) void gemm_out_mfma(
        const short* __restrict__ Wb, const float* __restrict__ bo,
        const short* __restrict__ wgt, const float* __restrict__ x,
        float* __restrict__ out) {
    __shared__ short lA[2][4096];
    __shared__ short lB[2][8192];
    const int n = blockIdx.x;               // 0..1599
    const int w = (n & 7) * 200 + (n >> 3);
    const int b = w / 200;
    const int r200 = w % 200;
    const int o0 = (r200 % 4) * 64;       // pt-major: o-tile fastest
    const int p0 = (r200 / 4) * 128;
    const int t = threadIdx.x;
    const int wid = t >> 6, lane = t & 63;
    const short* wgtb = wgt + (size_t)b * HW_ * 256;
    f32x4 acc[4][2] = {};

    OSTAGE(0, 0)
    #pragma unroll
    for (int kt = 0; kt < 4; ++kt) {
        const int cur = kt & 1;
        if (kt > 0) __builtin_amdgcn_s_barrier();
        if (kt < 3) { OSTAGE(cur ^ 1, (kt + 1) * 64) }
        if (kt < 3) { asm volatile("s_waitcnt vmcnt(6)" ::: "memory"); }
        else        { asm volatile("s_waitcnt vmcnt(0)" ::: "memory"); }
        __builtin_amdgcn_sched_barrier(0);
        __builtin_amdgcn_s_barrier();
        OCOMPUTE(cur)
    }

    #pragma unroll
    for (int m = 0; m < 4; ++m) {
        int oc = o0 + m * 16 + (lane >> 4) * 4;
        float4 bias = *(const float4*)(bo + oc);
        float br[4] = {bias.x, bias.y, bias.z, bias.w};
        #pragma unroll
        for (int nn = 0; nn < 2; ++nn) {
            int p = p0 + wid * 32 + nn * 16 + (lane & 15);
            f32x4 a = acc[m][nn];
            #pragma unroll
            for (int reg = 0; reg < 4; ++reg) {
                size_t ad = ((size_t)b * C_ + oc + reg) * HW_ + p;
                out[ad] = a[reg] + br[reg] + x[ad];
            }
        }
    }
}

// ---------------------------------------------------------------------------
// Launch
// ---------------------------------------------------------------------------
extern "C" void kernel_launch(void* const* d_in, const int* in_sizes, int n_in,
                              void* d_out, int out_size, void* d_ws, size_t ws_size,
                              hipStream_t stream) {
    const float* x    = (const float*)d_in[0];
    const float* Wv   = (const float*)d_in[1];
    const float* bv   = (const float*)d_in[2];
    const float* Woff = (const float*)d_in[3];
    const float* boff = (const float*)d_in[4];
    const float* Wa   = (const float*)d_in[5];
    const float* ba   = (const float*)d_in[6];
    const float* Wo   = (const float*)d_in[7];
    const float* bo   = (const float*)d_in[8];
    float* out = (float*)d_out;
    char* base = (char*)d_ws;

    short*    WcatBf = (short*)(base);               //   196608
    short*    WoBf   = (short*)(base + 196608);      //   131072
    float*    bcat   = (float*)(base + 327680);      //     1536 (+pad)
    short*    xT     = (short*)(base + 329728);      // 26214400
    short*    val    = (short*)(base + 26544128);    // 26214400
    _Float16* meta   = (_Float16*)(base + 52758528); //  9830400 (f16)
    short*    wbuf   = (short*)(base + 72419328);    // 26214400

    prep_and_transpose<<<dim3(3840), dim3(256), 0, stream>>>(
        Wv, bv, Woff, boff, Wa, ba, Wo, x, WcatBf, WoBf, bcat, xT);
    gemm_proj_mfma<<<dim3(1200), dim3(256), 0, stream>>>(WcatBf, bcat, xT, val, meta);
    sample_kern<<<dim3(6400), dim3(256), 0, stream>>>(val, meta, wbuf);
    gemm_out_mfma<<<dim3(1600), dim3(256), 0, stream>>>(WoBf, bo, wbuf, x, out);
}